// Round 10
// baseline (626.428 us; speedup 1.0000x reference)
//
#include <hip/hip_runtime.h>

typedef unsigned short u16;
typedef unsigned int u32;

using bf16x8 = __attribute__((ext_vector_type(8))) __bf16;
using f32x4  = __attribute__((ext_vector_type(4))) float;
using u16x8  = __attribute__((ext_vector_type(8))) u16;

#define BB 4
#define TT 4096
#define DD 2048
#define MM 16384
#define KK 2048
#define NN 4096
#define NCHUNK 16
#define CLEN 256

__device__ __forceinline__ u16 f2bf(float f) {
    u32 u = __float_as_uint(f);
    u32 r = (u + 0x7FFFu + ((u >> 16) & 1u)) >> 16;
    return (u16)r;
}

__device__ __forceinline__ void gload_lds16(const void* g, void* l) {
    __builtin_amdgcn_global_load_lds(
        (const __attribute__((address_space(1))) void*)g,
        (__attribute__((address_space(3))) void*)l, 16, 0, 0);
}

// ---------------- fp32 -> bf16 convert (8 elems/thread) ----------------
__global__ __launch_bounds__(256) void cvt_kernel(const float* __restrict__ in,
                                                  u16* __restrict__ out, int n8) {
    int i = blockIdx.x * 256 + threadIdx.x;
    if (i >= n8) return;
    const f32x4* p = (const f32x4*)in + (size_t)i * 2;
    f32x4 a = p[0], b = p[1];
    u16x8 o;
    o[0] = f2bf(a[0]); o[1] = f2bf(a[1]); o[2] = f2bf(a[2]); o[3] = f2bf(a[3]);
    o[4] = f2bf(b[0]); o[5] = f2bf(b[1]); o[6] = f2bf(b[2]); o[7] = f2bf(b[3]);
    *((u16x8*)out + i) = o;
}

// W convert with channel interleave: out row 2e+gate = in row e
__global__ __launch_bounds__(256) void cvtw_kernel(const float* __restrict__ in,
                                                   u16* __restrict__ out, int gate) {
    int i = blockIdx.x * 256 + threadIdx.x;
    int row = i >> 8;
    int col8 = i & 255;
    const f32x4* p = (const f32x4*)in + (size_t)i * 2;
    f32x4 a = p[0], b = p[1];
    u16x8 o;
    o[0] = f2bf(a[0]); o[1] = f2bf(a[1]); o[2] = f2bf(a[2]); o[3] = f2bf(a[3]);
    o[4] = f2bf(b[0]); o[5] = f2bf(b[1]); o[6] = f2bf(b[2]); o[7] = f2bf(b[3]);
    size_t oidx = (((size_t)row * 2 + gate) << 11) + (size_t)col8 * 8;
    *(u16x8*)(out + oidx) = o;
}

// ---------------- concat-N GEMM, m201 geometry + R3 lockstep rhythm ----------------
// C[16384, 4096] = Xb @ Wc^T (Wc rows interleaved: 2e=W_in[e], 2e+1=W_gate[e]).
// Tile 256x256, BK=64, 8 waves (2m x 4n), wave tile 128x64, acc 32 f32x4.
// 4 phases/K-tile: reads {8,8,4,4} (B read once, reused 2 phases), 16 MFMA each.
// 2-deep LDS ring (128 KB); all 8 stages issued in ph0/ph1; vmcnt(0) at tile end.
#define BKc 64
#define NTc (KK / BKc)   // 32 K-tiles

#define MF(a_, b_, c_) __builtin_amdgcn_mfma_f32_16x16x32_bf16(a_, b_, c_, 0, 0, 0)

__global__ __launch_bounds__(512, 2) void gemm_cat8(
    const u16* __restrict__ xb, const u16* __restrict__ wc,
    const float* __restrict__ b_in, const float* __restrict__ b_gate,
    const float* __restrict__ lam, u32* __restrict__ pair)
{
    __shared__ u16 As[2][256 * BKc];   // 2 x 32 KB
    __shared__ u16 Bs[2][256 * BKc];   // 2 x 32 KB  (128 KB)

    const int tid = threadIdx.x;
    const int bid = blockIdx.x;
    const int cpx = gridDim.x >> 3;               // 1024/8 -> bijective
    const int swz = (bid & 7) * cpx + (bid >> 3);
    const int nt = swz & 15;    // 16 n-tiles
    const int mt = swz >> 4;    // 64 m-tiles
    const size_t m0 = (size_t)mt * 256;
    const size_t n0 = (size_t)nt * 256;

    const int lane = tid & 63;
    const int wid = tid >> 6;
    const int wr = wid >> 2;          // 0..1 -> m offset wr*128
    const int wcv = (wid & 3) * 64;   // n offset
    const int r15 = lane & 15;
    const int s4 = lane >> 4;         // 0..3

    // staging: gload g covers chunks L = g*512+tid in [0,2048); row=L>>3 (0..255),
    // LDS chunk c=L&7; global chunk = c ^ (row&7)  (XOR-swizzle, LDS dest linear)
    const u16 *gA[4], *gB[4];
#pragma unroll
    for (int g = 0; g < 4; g++) {
        int L = g * 512 + tid;
        int row = L >> 3;
        int cs = (L & 7) ^ (row & 7);
        gA[g] = xb + (m0 + row) * (size_t)KK + cs * 8;
        gB[g] = wc + (n0 + row) * (size_t)KK + cs * 8;
    }

#define ST_A01(t) do { int _b = (t) & 1; size_t _k = (size_t)(t) * BKc; \
        gload_lds16(gA[0] + _k, &As[_b][(0 * 512 + tid) * 8]); \
        gload_lds16(gA[1] + _k, &As[_b][(1 * 512 + tid) * 8]); } while (0)
#define ST_A23(t) do { int _b = (t) & 1; size_t _k = (size_t)(t) * BKc; \
        gload_lds16(gA[2] + _k, &As[_b][(2 * 512 + tid) * 8]); \
        gload_lds16(gA[3] + _k, &As[_b][(3 * 512 + tid) * 8]); } while (0)
#define ST_B01(t) do { int _b = (t) & 1; size_t _k = (size_t)(t) * BKc; \
        gload_lds16(gB[0] + _k, &Bs[_b][(0 * 512 + tid) * 8]); \
        gload_lds16(gB[1] + _k, &Bs[_b][(1 * 512 + tid) * 8]); } while (0)
#define ST_B23(t) do { int _b = (t) & 1; size_t _k = (size_t)(t) * BKc; \
        gload_lds16(gB[2] + _k, &Bs[_b][(2 * 512 + tid) * 8]); \
        gload_lds16(gB[3] + _k, &Bs[_b][(3 * 512 + tid) * 8]); } while (0)

    // read offsets (elements): row*64 + (chunk ^ (row&7))*8, chunk = ks*4+s4
    int aR[8][2], bR[4][2];
#pragma unroll
    for (int ks = 0; ks < 2; ks++) {
#pragma unroll
        for (int mi = 0; mi < 8; mi++) {
            int row = wr * 128 + mi * 16 + r15;
            aR[mi][ks] = row * 64 + (((ks * 4 + s4) ^ (row & 7)) << 3);
        }
#pragma unroll
        for (int ni = 0; ni < 4; ni++) {
            int row = wcv + ni * 16 + r15;
            bR[ni][ks] = row * 64 + (((ks * 4 + s4) ^ (row & 7)) << 3);
        }
    }

    f32x4 acc[8][4];
#pragma unroll
    for (int i = 0; i < 8; i++)
#pragma unroll
        for (int j = 0; j < 4; j++) acc[i][j] = (f32x4){0.f, 0.f, 0.f, 0.f};

    bf16x8 aF[4], bv0[4], bv1[4];

#define LGKM0() do { asm volatile("s_waitcnt lgkmcnt(0)" ::: "memory"); \
                     __builtin_amdgcn_sched_barrier(0); } while (0)
#define BURST(base, bv) do { __builtin_amdgcn_s_setprio(1); \
        _Pragma("unroll") for (int m = 0; m < 4; m++) \
        _Pragma("unroll") for (int n = 0; n < 4; n++) \
            acc[m + (base)][n] = MF(aF[m], bv[n], acc[m + (base)][n]); \
        __builtin_amdgcn_s_setprio(0); } while (0)

    // prologue: stage tile 0, drain
    ST_A01(0); ST_A23(0); ST_B01(0); ST_B23(0);
    asm volatile("s_waitcnt vmcnt(0)" ::: "memory");
    __builtin_amdgcn_s_barrier();

#pragma unroll 2
    for (int t = 0; t < NTc; ++t) {
        const int s = t & 1;
        const u16* Ab = &As[s][0];
        const u16* Bb = &Bs[s][0];
        // ph0: A[0-3]ks0 + B[0-3]ks0 (8 reads); stage A01(t+1); burst A03xB ks0
#pragma unroll
        for (int m = 0; m < 4; m++) aF[m] = *(const bf16x8*)&Ab[aR[m][0]];
#pragma unroll
        for (int n = 0; n < 4; n++) bv0[n] = *(const bf16x8*)&Bb[bR[n][0]];
        if (t < NTc - 1) { ST_A01(t + 1); ST_B01(t + 1); }
        __builtin_amdgcn_s_barrier();
        LGKM0();
        BURST(0, bv0);
        __builtin_amdgcn_s_barrier();
        // ph1: A[4-7]ks0 + B[0-3]ks1 (8 reads); stage A23,B23(t+1); burst A47xB ks0
#pragma unroll
        for (int m = 0; m < 4; m++) aF[m] = *(const bf16x8*)&Ab[aR[m + 4][0]];
#pragma unroll
        for (int n = 0; n < 4; n++) bv1[n] = *(const bf16x8*)&Bb[bR[n][1]];
        if (t < NTc - 1) { ST_A23(t + 1); ST_B23(t + 1); }
        __builtin_amdgcn_s_barrier();
        LGKM0();
        BURST(4, bv0);
        __builtin_amdgcn_s_barrier();
        // ph2: A[0-3]ks1 (4 reads); burst A03xB ks1
#pragma unroll
        for (int m = 0; m < 4; m++) aF[m] = *(const bf16x8*)&Ab[aR[m][1]];
        __builtin_amdgcn_s_barrier();
        LGKM0();
        BURST(0, bv1);
        __builtin_amdgcn_s_barrier();
        // ph3: A[4-7]ks1 (4 reads); burst A47xB ks1; tile-end drain
#pragma unroll
        for (int m = 0; m < 4; m++) aF[m] = *(const bf16x8*)&Ab[aR[m + 4][1]];
        __builtin_amdgcn_s_barrier();
        LGKM0();
        BURST(4, bv1);
        if (t < NTc - 1) asm volatile("s_waitcnt vmcnt(0)" ::: "memory");
        __builtin_amdgcn_s_barrier();
    }

    // ---- epilogue: paired-gate math via shfl_xor(1) (R6-verified) ----
    const int gate = r15 & 1;
#pragma unroll
    for (int ni = 0; ni < 4; ni++) {
        size_t n = n0 + wcv + ni * 16 + r15;
        size_t ch = n >> 1;
        float spl = 8.0f * log1pf(__expf(lam[ch]));
        float biv = b_in[ch];
        float bgv = b_gate[ch];
#pragma unroll
        for (int mi = 0; mi < 8; mi++) {
#pragma unroll
            for (int r = 0; r < 4; r++) {
                float own = acc[mi][ni][r];
                float oth = __shfl_xor(own, 1, 64);
                float ig = (gate ? oth : own) + biv;
                float rg = (gate ? own : oth) + bgv;
                float sigr = 1.f / (1.f + __expf(-rg));
                float g = spl * sigr;
                float beta = sqrtf(1.f - __expf(-2.f * g) + 1e-6f);
                size_t m = m0 + wr * 128 + mi * 16 + s4 * 4 + r;
                float xv = __uint_as_float((u32)xb[m * KK + ch] << 16);
                float xbeta = beta * (1.f / (1.f + __expf(-ig))) * xv;
                u32 pk = (u32)f2bf(g) | (((u32)f2bf(xbeta)) << 16);
                if (!gate) pair[m * DD + ch] = pk;
            }
        }
    }
#undef ST_A01
#undef ST_A23
#undef ST_B01
#undef ST_B23
#undef BURST
}

// ---------------- chunked scan ----------------
// pair layout [B,T,D]: low16 = bf16(g), high16 = bf16(xbeta); alpha = exp(-g)
__global__ __launch_bounds__(256) void scanA(const u32* __restrict__ pair,
                                             float* __restrict__ aggG,
                                             float* __restrict__ aggB) {
    int gid = blockIdx.x * 256 + threadIdx.x;   // 131072
    int e = gid & (DD - 1);
    int rest = gid >> 11;     // 0..63
    int b = rest & 3;
    int c = rest >> 2;        // 0..15
    const u32* p = pair + ((size_t)(b * TT + c * CLEN)) * DD + e;
    float gsum = 0.f, h = 0.f;
#pragma unroll 4
    for (int t = 0; t < CLEN; ++t) {
        u32 v = *p; p += DD;
        float gf = __uint_as_float(v << 16);
        float xbv = __uint_as_float(v & 0xFFFF0000u);
        gsum += gf;
        h = fmaf(__expf(-gf), h, xbv);
    }
    int idx = ((b * NCHUNK + c) << 11) | e;
    aggG[idx] = gsum;
    aggB[idx] = h;
}

__global__ __launch_bounds__(256) void scanB(const float* __restrict__ aggG,
                                             const float* __restrict__ aggB,
                                             float* __restrict__ carry) {
    int gid = blockIdx.x * 256 + threadIdx.x;   // 8192
    int e = gid & (DD - 1);
    int b = gid >> 11;
    float h = 0.f;
#pragma unroll
    for (int c = 0; c < NCHUNK; ++c) {
        int idx = ((b * NCHUNK + c) << 11) | e;
        carry[idx] = h;
        h = fmaf(__expf(-aggG[idx]), h, aggB[idx]);
    }
}

__global__ __launch_bounds__(256) void scanC(const u32* __restrict__ pair,
                                             const float* __restrict__ carry,
                                             float* __restrict__ out) {
    int gid = blockIdx.x * 256 + threadIdx.x;   // 131072
    int e = gid & (DD - 1);
    int rest = gid >> 11;
    int b = rest & 3;
    int c = rest >> 2;
    const u32* p = pair + ((size_t)(b * TT + c * CLEN)) * DD + e;
    float* o = out + ((size_t)(b * TT + c * CLEN)) * DD + e;
    float h = carry[((b * NCHUNK + c) << 11) | e];
#pragma unroll 4
    for (int t = 0; t < CLEN; ++t) {
        u32 v = *p; p += DD;
        float gf = __uint_as_float(v << 16);
        float xbv = __uint_as_float(v & 0xFFFF0000u);
        h = fmaf(__expf(-gf), h, xbv);
        *o = h; o += DD;
    }
}

extern "C" void kernel_launch(void* const* d_in, const int* in_sizes, int n_in,
                              void* d_out, int out_size, void* d_ws, size_t ws_size,
                              hipStream_t stream) {
    const float* x      = (const float*)d_in[0];
    const float* W_in   = (const float*)d_in[1];
    const float* b_in   = (const float*)d_in[2];
    const float* W_gate = (const float*)d_in[3];
    const float* b_gate = (const float*)d_in[4];
    const float* lam    = (const float*)d_in[5];
    float* out = (float*)d_out;

    char* ws = (char*)d_ws;
    u16* xb   = (u16*)(ws);                  // 67,108,864 B
    u16* wc   = (u16*)(ws + 67108864);       // 16,777,216 B (interleaved [4096][2048] bf16)
    u32* pair = (u32*)(ws + 83886080);       // 134,217,728 B
    float* aggG  = (float*)(ws + 218103808); // 524,288 B
    float* aggB  = (float*)(ws + 218628096); // 524,288 B
    float* carry = (float*)(ws + 219152384); // 524,288 B

    cvt_kernel<<<16384, 256, 0, stream>>>(x, xb, MM * KK / 8);
    cvtw_kernel<<<2048, 256, 0, stream>>>(W_in, wc, 0);
    cvtw_kernel<<<2048, 256, 0, stream>>>(W_gate, wc, 1);
    gemm_cat8<<<(MM / 256) * (NN / 256), 512, 0, stream>>>(xb, wc, b_in, b_gate, lam, pair);
    scanA<<<BB * DD * NCHUNK / 256, 256, 0, stream>>>(pair, aggG, aggB);
    scanB<<<BB * DD / 256, 256, 0, stream>>>(aggG, aggB, carry);
    scanC<<<BB * DD * NCHUNK / 256, 256, 0, stream>>>(pair, carry, out);
}

// Round 11
// 489.142 us; speedup vs baseline: 1.2807x; 1.2807x over previous
//
#include <hip/hip_runtime.h>

typedef unsigned short u16;
typedef unsigned int u32;

using bf16x8 = __attribute__((ext_vector_type(8))) __bf16;
using f32x4  = __attribute__((ext_vector_type(4))) float;
using f32x16 = __attribute__((ext_vector_type(16))) float;
using u16x8  = __attribute__((ext_vector_type(8))) u16;

#define BB 4
#define TT 4096
#define DD 2048
#define MM 16384
#define KK 2048
#define NCHUNK 32
#define CLEN 128

__device__ __forceinline__ u16 f2bf(float f) {
    u32 u = __float_as_uint(f);
    u32 r = (u + 0x7FFFu + ((u >> 16) & 1u)) >> 16;
    return (u16)r;
}

__device__ __forceinline__ void gload_lds16(const void* g, void* l) {
    __builtin_amdgcn_global_load_lds(
        (const __attribute__((address_space(1))) void*)g,
        (__attribute__((address_space(3))) void*)l, 16, 0, 0);
}

// ---------------- fp32 -> bf16 convert (8 elems/thread) ----------------
__global__ __launch_bounds__(256) void cvt_kernel(const float* __restrict__ in,
                                                  u16* __restrict__ out, int n8) {
    int i = blockIdx.x * 256 + threadIdx.x;
    if (i >= n8) return;
    const f32x4* p = (const f32x4*)in + (size_t)i * 2;
    f32x4 a = p[0], b = p[1];
    u16x8 o;
    o[0] = f2bf(a[0]); o[1] = f2bf(a[1]); o[2] = f2bf(a[2]); o[3] = f2bf(a[3]);
    o[4] = f2bf(b[0]); o[5] = f2bf(b[1]); o[6] = f2bf(b[2]); o[7] = f2bf(b[3]);
    *((u16x8*)out + i) = o;
}

// ---------------- fused dual GEMM (32x32x16 MFMA, R3 rhythm) + gate epilogue ----------------
// Tile 256(M) x 128(e), BK=32, 8 waves (2M x 4N), wave tile 128m x 32e x 2 gates.
// acc = 4mi x 2gate x f32x16 = 128 regs. Per K-step: ph0 {8 reads + ST_A, bar,
// lgkm0, 8 MFMA(kh0), bar}; ph1 {4 reads + ST_B, bar, lgkm0, 8 MFMA(kh1),
// vmcnt(8), bar}. 4-deep ring, stage distance 3 (R3-verified schedule).
#define BMg 256
#define BNg 128
#define BKg 32
#define NT (KK / BKg)   // 64 K-steps

#define MF32(a_, b_, c_) __builtin_amdgcn_mfma_f32_32x32x16_bf16(a_, b_, c_, 0, 0, 0)

__global__ __launch_bounds__(512, 2) void gemm_d32(
    const u16* __restrict__ xb, const u16* __restrict__ wib, const u16* __restrict__ wgb,
    const float* __restrict__ b_in, const float* __restrict__ b_gate,
    const float* __restrict__ lam, u32* __restrict__ pair)
{
    __shared__ u16 As[4][BMg * BKg];   // 4 x 16 KB
    __shared__ u16 Bi[4][BNg * BKg];   // 4 x 8 KB
    __shared__ u16 Bg[4][BNg * BKg];   // 4 x 8 KB   (128 KB)

    const int tid = threadIdx.x;
    const int bid = blockIdx.x;
    const int cpx = gridDim.x >> 3;               // 1024/8 -> bijective
    const int swz = (bid & 7) * cpx + (bid >> 3);
    const int et = swz & 15;
    const int mt = swz >> 4;
    const size_t m0 = (size_t)mt * BMg;
    const size_t e0 = (size_t)et * BNg;

    const int lane = tid & 63;
    const int w = tid >> 6;
    const int wr = w >> 2;        // 0..1 -> m offset wr*128
    const int wc = w & 3;         // 0..3 -> e offset wc*32
    const int l31 = lane & 31;
    const int lhi = lane >> 5;    // 0..1

    // ---- staging maps: chunk L -> row L>>2, LDS chunk L&3; global chunk = (L&3)^(row&3)
    const u16 *gA[2], *gBi, *gBg;
#pragma unroll
    for (int j = 0; j < 2; j++) {
        int L = j * 512 + tid;
        int row = L >> 2;
        int sc = (L & 3) ^ (row & 3);
        gA[j] = xb + (m0 + row) * (size_t)KK + sc * 8;
    }
    {
        int row = tid >> 2;
        int sc = (tid & 3) ^ (row & 3);
        gBi = wib + (e0 + row) * (size_t)KK + sc * 8;
        gBg = wgb + (e0 + row) * (size_t)KK + sc * 8;
    }

#define ST_A(t) do { int _s = (t) & 3; size_t _k = (size_t)(t) * BKg; \
        gload_lds16(gA[0] + _k, &As[_s][tid * 8]); \
        gload_lds16(gA[1] + _k, &As[_s][4096 + tid * 8]); } while (0)
#define ST_B(t) do { int _s = (t) & 3; size_t _k = (size_t)(t) * BKg; \
        gload_lds16(gBi + _k, &Bi[_s][tid * 8]); \
        gload_lds16(gBg + _k, &Bg[_s][tid * 8]); } while (0)

    // ---- read offsets: row*32 + ((kh*2+lhi) ^ (l31&3))*8  (row&3 == l31&3)
    int cswz[2];
#pragma unroll
    for (int kh = 0; kh < 2; kh++) cswz[kh] = (((kh * 2 + lhi) ^ (l31 & 3)) << 3);
    int aR[4], bR;
#pragma unroll
    for (int mi = 0; mi < 4; mi++) aR[mi] = (wr * 128 + mi * 32 + l31) << 5;
    bR = (wc * 32 + l31) << 5;

    f32x16 acc[4][2];   // [mi][gate]
#pragma unroll
    for (int mi = 0; mi < 4; mi++)
#pragma unroll
        for (int g = 0; g < 2; g++)
#pragma unroll
            for (int r = 0; r < 16; r++) acc[mi][g][r] = 0.f;

    bf16x8 aF[4], bv[4];   // bv = {Bi kh0, Bi kh1, Bg kh0, Bg kh1}

#define LGKM0() do { asm volatile("s_waitcnt lgkmcnt(0)" ::: "memory"); \
                     __builtin_amdgcn_sched_barrier(0); } while (0)
#define BURST(khsel) do { __builtin_amdgcn_s_setprio(1); \
        _Pragma("unroll") for (int mi = 0; mi < 4; mi++) { \
            acc[mi][0] = MF32(aF[mi], bv[0 + (khsel)], acc[mi][0]); \
            acc[mi][1] = MF32(aF[mi], bv[2 + (khsel)], acc[mi][1]); } \
        __builtin_amdgcn_s_setprio(0); } while (0)

    // prologue: stage K-steps 0,1,2
    ST_A(0); ST_B(0);
    ST_A(1); ST_B(1);
    ST_A(2); ST_B(2);
    asm volatile("s_waitcnt vmcnt(8)" ::: "memory");   // step 0 resident
    __builtin_amdgcn_s_barrier();

#pragma unroll 4
    for (int t = 0; t < NT - 3; ++t) {
        const int s = t & 3;
        // ph0: 8 reads (A kh0 x4, B all x4) + ST_A(t+3); burst kh0
#pragma unroll
        for (int mi = 0; mi < 4; mi++) aF[mi] = *(const bf16x8*)&As[s][aR[mi] + cswz[0]];
        bv[0] = *(const bf16x8*)&Bi[s][bR + cswz[0]];
        bv[1] = *(const bf16x8*)&Bi[s][bR + cswz[1]];
        bv[2] = *(const bf16x8*)&Bg[s][bR + cswz[0]];
        bv[3] = *(const bf16x8*)&Bg[s][bR + cswz[1]];
        ST_A(t + 3);
        __builtin_amdgcn_s_barrier();
        LGKM0();
        BURST(0);
        __builtin_amdgcn_s_barrier();
        // ph1: 4 reads (A kh1) + ST_B(t+3); burst kh1; counted vmcnt
#pragma unroll
        for (int mi = 0; mi < 4; mi++) aF[mi] = *(const bf16x8*)&As[s][aR[mi] + cswz[1]];
        ST_B(t + 3);
        __builtin_amdgcn_s_barrier();
        LGKM0();
        BURST(1);
        asm volatile("s_waitcnt vmcnt(8)" ::: "memory");
        __builtin_amdgcn_s_barrier();
    }
    // tail: t = NT-3..NT-1, no staging; drain 8 -> 4 -> 0
#pragma unroll 1
    for (int t = NT - 3; t < NT; ++t) {
        const int s = t & 3;
#pragma unroll
        for (int mi = 0; mi < 4; mi++) aF[mi] = *(const bf16x8*)&As[s][aR[mi] + cswz[0]];
        bv[0] = *(const bf16x8*)&Bi[s][bR + cswz[0]];
        bv[1] = *(const bf16x8*)&Bi[s][bR + cswz[1]];
        bv[2] = *(const bf16x8*)&Bg[s][bR + cswz[0]];
        bv[3] = *(const bf16x8*)&Bg[s][bR + cswz[1]];
        __builtin_amdgcn_s_barrier();
        LGKM0();
        BURST(0);
        __builtin_amdgcn_s_barrier();
#pragma unroll
        for (int mi = 0; mi < 4; mi++) aF[mi] = *(const bf16x8*)&As[s][aR[mi] + cswz[1]];
        __builtin_amdgcn_s_barrier();
        LGKM0();
        BURST(1);
        if (t == NT - 3)      asm volatile("s_waitcnt vmcnt(4)" ::: "memory");
        else if (t == NT - 2) asm volatile("s_waitcnt vmcnt(0)" ::: "memory");
        __builtin_amdgcn_s_barrier();
    }

    // ---- epilogue: col = e0 + wc*32 + l31 (one channel per lane);
    //      row = m0 + wr*128 + mi*32 + (r&3) + 8*(r>>2) + 4*lhi  (m74/m101 C-layout)
    {
        size_t e = e0 + wc * 32 + l31;
        float spl = 8.0f * log1pf(__expf(lam[e]));
        float biv = b_in[e];
        float bgv = b_gate[e];
#pragma unroll
        for (int mi = 0; mi < 4; mi++) {
#pragma unroll
            for (int r = 0; r < 16; r++) {
                size_t m = m0 + wr * 128 + mi * 32 + (r & 3) + 8 * (r >> 2) + 4 * lhi;
                float ig = acc[mi][0][r] + biv;
                float rg = acc[mi][1][r] + bgv;
                float sigr = 1.f / (1.f + __expf(-rg));
                float g = spl * sigr;
                float beta = sqrtf(1.f - __expf(-2.f * g) + 1e-6f);
                float xv = __uint_as_float((u32)xb[m * KK + e] << 16);  // L2-hot bf16 x
                float xbeta = beta * (1.f / (1.f + __expf(-ig))) * xv;
                u32 pk = (u32)f2bf(g) | (((u32)f2bf(xbeta)) << 16);
                pair[m * DD + e] = pk;
            }
        }
    }
#undef ST_A
#undef ST_B
#undef BURST
}

// ---------------- chunked scan (32 chunks x 128 steps) ----------------
// pair layout [B,T,D]: low16 = bf16(g), high16 = bf16(xbeta); alpha = exp(-g)
__global__ __launch_bounds__(256) void scanA(const u32* __restrict__ pair,
                                             float* __restrict__ aggG,
                                             float* __restrict__ aggB) {
    int gid = blockIdx.x * 256 + threadIdx.x;   // 262144
    int e = gid & (DD - 1);
    int rest = gid >> 11;     // 0..127
    int b = rest & 3;
    int c = rest >> 2;        // 0..31
    const u32* p = pair + ((size_t)(b * TT + c * CLEN)) * DD + e;
    float gsum = 0.f, h = 0.f;
#pragma unroll 4
    for (int t = 0; t < CLEN; ++t) {
        u32 v = *p; p += DD;
        float gf = __uint_as_float(v << 16);
        float xbv = __uint_as_float(v & 0xFFFF0000u);
        gsum += gf;
        h = fmaf(__expf(-gf), h, xbv);
    }
    int idx = ((b * NCHUNK + c) << 11) | e;
    aggG[idx] = gsum;
    aggB[idx] = h;
}

__global__ __launch_bounds__(256) void scanB(const float* __restrict__ aggG,
                                             const float* __restrict__ aggB,
                                             float* __restrict__ carry) {
    int gid = blockIdx.x * 256 + threadIdx.x;   // 8192
    int e = gid & (DD - 1);
    int b = gid >> 11;
    float h = 0.f;
#pragma unroll
    for (int c = 0; c < NCHUNK; ++c) {
        int idx = ((b * NCHUNK + c) << 11) | e;
        carry[idx] = h;
        h = fmaf(__expf(-aggG[idx]), h, aggB[idx]);
    }
}

__global__ __launch_bounds__(256) void scanC(const u32* __restrict__ pair,
                                             const float* __restrict__ carry,
                                             float* __restrict__ out) {
    int gid = blockIdx.x * 256 + threadIdx.x;   // 262144
    int e = gid & (DD - 1);
    int rest = gid >> 11;
    int b = rest & 3;
    int c = rest >> 2;
    const u32* p = pair + ((size_t)(b * TT + c * CLEN)) * DD + e;
    float* o = out + ((size_t)(b * TT + c * CLEN)) * DD + e;
    float h = carry[((b * NCHUNK + c) << 11) | e];
#pragma unroll 4
    for (int t = 0; t < CLEN; ++t) {
        u32 v = *p; p += DD;
        float gf = __uint_as_float(v << 16);
        float xbv = __uint_as_float(v & 0xFFFF0000u);
        h = fmaf(__expf(-gf), h, xbv);
        *o = h; o += DD;
    }
}

extern "C" void kernel_launch(void* const* d_in, const int* in_sizes, int n_in,
                              void* d_out, int out_size, void* d_ws, size_t ws_size,
                              hipStream_t stream) {
    const float* x      = (const float*)d_in[0];
    const float* W_in   = (const float*)d_in[1];
    const float* b_in   = (const float*)d_in[2];
    const float* W_gate = (const float*)d_in[3];
    const float* b_gate = (const float*)d_in[4];
    const float* lam    = (const float*)d_in[5];
    float* out = (float*)d_out;

    char* ws = (char*)d_ws;
    u16* xb   = (u16*)(ws);                  // 67,108,864 B
    u16* wib  = (u16*)(ws + 67108864);       //  8,388,608 B (reused by aggregates after GEMM)
    u16* wgb  = (u16*)(ws + 75497472);       //  8,388,608 B
    u32* pair = (u32*)(ws + 83886080);       // 134,217,728 B
    // aggregates overlay the dead wib/wgb region (scan phase only): 1 MB each
    float* aggG  = (float*)(ws + 67108864);
    float* aggB  = (float*)(ws + 68157440);
    float* carry = (float*)(ws + 69206016);

    cvt_kernel<<<16384, 256, 0, stream>>>(x, xb, MM * KK / 8);
    cvt_kernel<<<2048, 256, 0, stream>>>(W_in, wib, DD * KK / 8);
    cvt_kernel<<<2048, 256, 0, stream>>>(W_gate, wgb, DD * KK / 8);
    gemm_d32<<<(MM / BMg) * (DD / BNg), 512, 0, stream>>>(xb, wib, wgb, b_in, b_gate, lam, pair);
    scanA<<<BB * DD * NCHUNK / 256, 256, 0, stream>>>(pair, aggG, aggB);
    scanB<<<BB * DD / 256, 256, 0, stream>>>(aggG, aggB, carry);
    scanC<<<BB * DD * NCHUNK / 256, 256, 0, stream>>>(pair, carry, out);
}